// Round 3
// baseline (112.493 us; speedup 1.0000x reference)
//
#include <hip/hip_runtime.h>
#include <math.h>

namespace {

constexpr int S = 100;
constexpr int NR = 800;
constexpr int RPB = 4;           // batch rows per block
constexpr int NTH = 1024;        // 16 waves
constexpr int IN_COLS = 2 + S;   // 102
constexpr int OUT_COLS = 3 + NR + 2 + S; // 905
constexpr float RGASF = 8314.46261815324f;
constexpr float ATMF = 101325.0f;

__device__ __forceinline__ float wave_sum(float v) {
#pragma unroll
  for (int off = 32; off; off >>= 1) v += __shfl_xor(v, off);
  return v;
}

__global__ __launch_bounds__(NTH, 8)
void chem_props_kernel(const float* __restrict__ TPY,
                       const float* __restrict__ mw,
                       const float* __restrict__ nasa_low,
                       const float* __restrict__ nasa_high,
                       const float* __restrict__ eff,
                       const float* __restrict__ i3b,
                       const float* __restrict__ visc_poly,
                       const float* __restrict__ cond_poly,
                       const float* __restrict__ bdiff_poly,
                       float* __restrict__ out)
{
  __shared__ __align__(16) float Xl[S][RPB];     // mole fractions
  __shared__ __align__(16) float u1l[S][RPB];    // X / sqrt(visc)
  __shared__ __align__(16) float u2l[S][RPB];    // X / visc
  __shared__ __align__(16) float viscl[S][RPB];
  __shared__ __align__(16) float svl[S][RPB];    // sqrt(visc)
  __shared__ __align__(16) float denoml[S][RPB];
  __shared__ __align__(16) float xjdl[S][RPB];
  __shared__ float mwl[S], imwl[S];
  __shared__ float pa[8][2];                     // phase-1 partials (y, y/mw)
  __shared__ float pb[8][5];                     // phase-2 partials
  __shared__ float rs_L[RPB], rs_cfac[RPB], rs_mW[RPB], rs_scale[RPB], rs_T[RPB];
  __shared__ float vsum[RPB];

  const int tid = threadIdx.x;
  const int wid = tid >> 6;
  const int lane = tid & 63;
  const int row0 = blockIdx.x * RPB;

  // zero the accumulators + load molecular weights
  if (tid < S * RPB) {
    (&denoml[0][0])[tid] = 0.0f;
    (&xjdl[0][0])[tid] = 0.0f;
  }
  if (tid < RPB) vsum[tid] = 0.0f;
  if (tid < S) {
    float m = mw[tid];
    mwl[tid] = m;
    imwl[tid] = 1.0f / m;
  }
  __syncthreads();

  // ============ Stage A: per-row species (2 waves per row, waves 0-7) ======
  float T = 0.f, P = 0.f, L = 0.f, y = 0.f, im = 0.f;
  int row = 0, half = 0, s = 0;
  bool valid = false;
  const float* rowp = nullptr;
  if (wid < 8) {
    row = wid & 3;
    half = wid >> 2;
    rowp = TPY + (size_t)(row0 + row) * IN_COLS;
    T = fmaxf(rowp[0], 200.0f);
    P = rowp[1];
    L = __logf(T);
    s = half * 64 + lane;
    valid = (s < S);
    y = valid ? fmaxf(rowp[2 + s], 0.0f) : 0.0f;
    im = valid ? imwl[s] : 0.0f;
    float py = wave_sum(y);
    float pw = wave_sum(y * im);
    if (lane == 0) { pa[wid][0] = py; pa[wid][1] = pw; }
  }
  __syncthreads();

  if (wid < 8) {
    float T2 = T * T, T3 = T2 * T, T4 = T2 * T2;
    float invT = 1.0f / T;
    float ysum = pa[row][0] + pa[row + 4][0];
    float wsum = pa[row][1] + pa[row + 4][1];
    float invy = 1.0f / ysum;
    float mW = ysum / wsum;                          // 1 / sum(Ynorm/mw)
    float cfac = P / (RGASF * T);
    float lnP = __logf(P * (1.0f / ATMF));

    const float* nasa = (T <= 1000.0f) ? nasa_low : nasa_high;

    float cpx = 0.0f, hy = 0.0f, sy = 0.0f, condA = 0.0f, condB = 0.0f;
    if (valid) {
      float yn = y * invy;
      float x = fmaxf(yn * mW * im, 1e-12f);
      const float* a = nasa + s * 7;
      float a0 = a[0], a1 = a[1], a2 = a[2], a3 = a[3],
            a4 = a[4], a5 = a[5], a6 = a[6];
      float cp = a0 + a1 * T + a2 * T2 + a3 * T3 + a4 * T4;
      float Ht = a0 + 0.5f * a1 * T + (1.0f / 3.0f) * a2 * T2
               + 0.25f * a3 * T3 + 0.2f * a4 * T4 + a5 * invT;
      float S0r = a0 * L + a1 * T + 0.5f * a2 * T2
                + (1.0f / 3.0f) * a3 * T3 + 0.25f * a4 * T4 + a6;
      cpx = cp * x;
      hy = Ht * im * yn;
      sy = (S0r - __logf(x) - lnP) * im * yn;

      float v = visc_poly[0 * S + s];
      v = fmaf(v, L, visc_poly[1 * S + s]);
      v = fmaf(v, L, visc_poly[2 * S + s]);
      v = fmaf(v, L, visc_poly[3 * S + s]);
      v = fmaf(v, L, visc_poly[4 * S + s]);
      float c = cond_poly[0 * S + s];
      c = fmaf(c, L, cond_poly[1 * S + s]);
      c = fmaf(c, L, cond_poly[2 * S + s]);
      c = fmaf(c, L, cond_poly[3 * S + s]);
      c = fmaf(c, L, cond_poly[4 * S + s]);
      condA = x * c;
      condB = x / c;
      float sv = sqrtf(v);
      Xl[s][row] = x;
      viscl[s][row] = v;
      svl[s][row] = sv;
      u1l[s][row] = x / sv;
      u2l[s][row] = x / v;
    }
    float scp = wave_sum(cpx);
    float sh = wave_sum(hy);
    float ss = wave_sum(sy);
    float sca = wave_sum(condA);
    float scb = wave_sum(condB);
    if (lane == 0) {
      pb[wid][0] = scp; pb[wid][1] = sh; pb[wid][2] = ss;
      pb[wid][3] = sca; pb[wid][4] = scb;
      if (half == 0) {
        rs_L[row] = L;
        rs_T[row] = T;
        rs_cfac[row] = cfac;
        rs_mW[row] = mW;
        rs_scale[row] = ATMF / (mW * P);
      }
    }
  }
  __syncthreads();

  // scalar outputs for the 4 rows
  if (tid < RPB) {
    const int r = tid;
    float scp = pb[r][0] + pb[r + 4][0];
    float sh  = pb[r][1] + pb[r + 4][1];
    float ss  = pb[r][2] + pb[r + 4][2];
    float sca = pb[r][3] + pb[r + 4][3];
    float scb = pb[r][4] + pb[r + 4][4];
    float* orow = out + (size_t)(row0 + r) * OUT_COLS;
    orow[0] = RGASF * scp;
    orow[1] = RGASF * rs_T[r] * sh;
    orow[2] = RGASF * ss;
    orow[3 + NR + 1] = 0.5f * (sca + 1.0f / scb);
  }

  // ============ Stage B: C_M2 = (C @ eff)*i3b + (1-i3b) ====================
  if (tid < NR) {
    const int q = tid;
    float acc[RPB];
#pragma unroll
    for (int b = 0; b < RPB; ++b) acc[b] = 0.0f;
#pragma unroll 4
    for (int s2 = 0; s2 < S; ++s2) {
      float e = eff[s2 * NR + q];
      float xv[RPB];
      *(float4*)&xv[0] = *(const float4*)&Xl[s2][0];
#pragma unroll
      for (int b = 0; b < RPB; ++b) acc[b] = fmaf(xv[b], e, acc[b]);
    }
    float t3 = i3b[q];
    float base = 1.0f - t3;
#pragma unroll
    for (int b = 0; b < RPB; ++b) {
      out[(size_t)(row0 + b) * OUT_COLS + 3 + q] = fmaf(acc[b] * rs_cfac[b], t3, base);
    }
  }

  // ============ Stage C1: viscosity mixing denominators ====================
  // denom[b][i] = sum_k A*X + 2*sv_i*(A*B4)(X/sv) + visc_i*(A*B4^2)(X/visc)
  if (tid < 1000) {
    const int i = tid % 100;
    const int kg = tid / 100;          // 10 k-groups of 10
    const float mwi = mwl[i];
    const float imwi = imwl[i];
    float d0[RPB], d1[RPB], d2[RPB];
#pragma unroll
    for (int b = 0; b < RPB; ++b) { d0[b] = 0; d1[b] = 0; d2[b] = 0; }
    const int k0 = kg * 10;
#pragma unroll 2
    for (int k = k0; k < k0 + 10; ++k) {
      float mwk = mwl[k];
      float A = 0.35355339059327373f *
                __builtin_amdgcn_rsqf(1.0f + mwi * imwl[k]);
      float B4 = sqrtf(sqrtf(mwk * imwi));
      float m1 = A * B4, m2 = m1 * B4;
      float xv[RPB], u1v[RPB], u2v[RPB];
      *(float4*)&xv[0] = *(const float4*)&Xl[k][0];
      *(float4*)&u1v[0] = *(const float4*)&u1l[k][0];
      *(float4*)&u2v[0] = *(const float4*)&u2l[k][0];
#pragma unroll
      for (int b = 0; b < RPB; ++b) {
        d0[b] = fmaf(A, xv[b], d0[b]);
        d1[b] = fmaf(m1, u1v[b], d1[b]);
        d2[b] = fmaf(m2, u2v[b], d2[b]);
      }
    }
#pragma unroll
    for (int b = 0; b < RPB; ++b) {
      float pden = d0[b] + 2.0f * svl[i][b] * d1[b] + viscl[i][b] * d2[b];
      atomicAdd(&denoml[i][b], pden);
    }
  }
  __syncthreads();

  // ============ Stage C2: viscosity sum | Stage D1: XjDjk ==================
  if (tid < 100 * RPB) {
    const int i = tid % 100;
    const int b = tid / 100;
    float contrib = Xl[i][b] * viscl[i][b] / denoml[i][b];
    atomicAdd(&vsum[b], contrib);
  }
  if (tid < 1000) {
    const int k = tid % 100;
    const int jg = tid / 100;          // 10 j-groups of 10
    float Lb[RPB];
#pragma unroll
    for (int b = 0; b < RPB; ++b) Lb[b] = rs_L[b];
    float acc[RPB];
#pragma unroll
    for (int b = 0; b < RPB; ++b) acc[b] = 0.0f;
    const int j0 = jg * 10;
#pragma unroll 2
    for (int j = j0; j < j0 + 10; ++j) {
      if (j == k) continue;  // diagonal cancels exactly in the reference
      float c0 = bdiff_poly[0 * 10000 + j * 100 + k];
      float c1 = bdiff_poly[1 * 10000 + j * 100 + k];
      float c2 = bdiff_poly[2 * 10000 + j * 100 + k];
      float c3 = bdiff_poly[3 * 10000 + j * 100 + k];
      float c4 = bdiff_poly[4 * 10000 + j * 100 + k];
      float xv[RPB];
      *(float4*)&xv[0] = *(const float4*)&Xl[j][0];
#pragma unroll
      for (int b = 0; b < RPB; ++b) {
        float p = fmaf(c0, Lb[b], c1);
        p = fmaf(p, Lb[b], c2);
        p = fmaf(p, Lb[b], c3);
        p = fmaf(p, Lb[b], c4);
        acc[b] = fmaf(xv[b], __builtin_amdgcn_rcpf(p), acc[b]);
      }
    }
#pragma unroll
    for (int b = 0; b < RPB; ++b) atomicAdd(&xjdl[k][b], acc[b]);
  }
  __syncthreads();

  // ============ Final writes ==============================================
  if (tid < RPB) {
    out[(size_t)(row0 + tid) * OUT_COLS + 3 + NR] = vsum[tid]; // viscosities
  }
  if (tid < 100 * RPB) {
    const int k = tid % 100;
    const int b = tid / 100;
    float num = rs_mW[b] - Xl[k][b] * mwl[k];        // XjWj
    float md = num / xjdl[k][b] * rs_scale[b];       // mix_diff
    out[(size_t)(row0 + b) * OUT_COLS + 3 + NR + 2 + k] = md;
  }
}

} // namespace

extern "C" void kernel_launch(void* const* d_in, const int* in_sizes, int n_in,
                              void* d_out, int out_size, void* d_ws, size_t ws_size,
                              hipStream_t stream) {
  const float* TPY        = (const float*)d_in[0];
  const float* mwp        = (const float*)d_in[1];
  const float* nasa_low   = (const float*)d_in[2];
  const float* nasa_high  = (const float*)d_in[3];
  const float* eff        = (const float*)d_in[4];
  const float* i3b        = (const float*)d_in[5];
  const float* visc_poly  = (const float*)d_in[6];
  const float* cond_poly  = (const float*)d_in[7];
  const float* bdiff_poly = (const float*)d_in[8];
  float* out = (float*)d_out;

  const int B = 2048;
  dim3 grid(B / RPB);
  chem_props_kernel<<<grid, NTH, 0, stream>>>(
      TPY, mwp, nasa_low, nasa_high, eff, i3b,
      visc_poly, cond_poly, bdiff_poly, out);
}

// Round 5
// 100.002 us; speedup vs baseline: 1.1249x; 1.1249x over previous
//
#include <hip/hip_runtime.h>
#include <math.h>

namespace {

constexpr int S = 100;
constexpr int NR = 800;
constexpr int RPB = 4;           // batch rows per block
constexpr int NTH = 512;         // 8 waves
constexpr int IN_COLS = 2 + S;   // 102
constexpr int OUT_COLS = 3 + NR + 2 + S; // 905
constexpr float RGASF = 8314.46261815324f;
constexpr float ATMF = 101325.0f;

__device__ __forceinline__ float wave_sum(float v) {
#pragma unroll
  for (int off = 32; off; off >>= 1) v += __shfl_xor(v, off);
  return v;
}

__device__ __forceinline__ float elem(const float4& v, int i) {
  return ((const float*)&v)[i];
}

__global__ __launch_bounds__(NTH, 4)
void chem_props_kernel(const float* __restrict__ TPY,
                       const float* __restrict__ mw,
                       const float* __restrict__ nasa_low,
                       const float* __restrict__ nasa_high,
                       const float* __restrict__ eff,
                       const float* __restrict__ i3b,
                       const float* __restrict__ visc_poly,
                       const float* __restrict__ cond_poly,
                       const float* __restrict__ bdiff_poly,
                       float* __restrict__ out)
{
  __shared__ __align__(16) float4 XL[S];   // X[s][b] quad
  __shared__ __align__(16) float4 U1[S];   // X/sqrt(visc)
  __shared__ __align__(16) float4 U2[S];   // X/visc
  __shared__ __align__(16) float4 VL[S];   // visc
  __shared__ float mwl[S];
  __shared__ float2 ilm[S];                // {1/mw, log2(mw)}
  __shared__ float pa[8][2];               // half-row partials (y, y/mw)
  __shared__ float pb[8][5];               // thermo partials
  __shared__ float rs_L[RPB], rs_cfac[RPB], rs_mW[RPB], rs_scale[RPB], rs_T[RPB];
  __shared__ float psum[2][RPB];           // viscosity-sum wave partials

  const int tid = threadIdx.x;
  const int wid = tid >> 6;
  const int lane = tid & 63;
  const int row0 = blockIdx.x * RPB;

  if (tid < S) {
    float m = mw[tid];
    mwl[tid] = m;
    ilm[tid] = make_float2(1.0f / m, __log2f(m));
  }
  __syncthreads();

  // ============ Stage A: per-row species state (2 waves per row) ===========
  const int row = wid & 3;
  const int half = wid >> 2;
  const float* rowp = TPY + (size_t)(row0 + row) * IN_COLS;
  float T = fmaxf(rowp[0], 200.0f);
  float P = rowp[1];
  float L = __logf(T);
  const int s = half * 64 + lane;
  const bool valid = (s < S);
  float y = valid ? fmaxf(rowp[2 + s], 0.0f) : 0.0f;
  float im = valid ? ilm[s].x : 0.0f;
  {
    float py = wave_sum(y);
    float pw = wave_sum(y * im);
    if (lane == 0) { pa[wid][0] = py; pa[wid][1] = pw; }
  }
  __syncthreads();
  {
    float T2 = T * T, T3 = T2 * T, T4 = T2 * T2;
    float invT = 1.0f / T;
    float ysum = pa[row][0] + pa[row + 4][0];
    float wsum = pa[row][1] + pa[row + 4][1];
    float invy = 1.0f / ysum;
    float mW = ysum / wsum;
    float cfac = P / (RGASF * T);
    float lnP = __logf(P * (1.0f / ATMF));
    const float* nasa = (T <= 1000.0f) ? nasa_low : nasa_high;

    float cpx = 0.0f, hy = 0.0f, sy = 0.0f, condA = 0.0f, condB = 0.0f;
    if (valid) {
      float yn = y * invy;
      float x = fmaxf(yn * mW * im, 1e-12f);
      const float* a = nasa + s * 7;
      float a0 = a[0], a1 = a[1], a2 = a[2], a3 = a[3],
            a4 = a[4], a5 = a[5], a6 = a[6];
      float cp = a0 + a1 * T + a2 * T2 + a3 * T3 + a4 * T4;
      float Ht = a0 + 0.5f * a1 * T + (1.0f / 3.0f) * a2 * T2
               + 0.25f * a3 * T3 + 0.2f * a4 * T4 + a5 * invT;
      float S0r = a0 * L + a1 * T + 0.5f * a2 * T2
                + (1.0f / 3.0f) * a3 * T3 + 0.25f * a4 * T4 + a6;
      cpx = cp * x;
      hy = Ht * im * yn;
      sy = (S0r - __logf(x) - lnP) * im * yn;

      float v = visc_poly[0 * S + s];
      v = fmaf(v, L, visc_poly[1 * S + s]);
      v = fmaf(v, L, visc_poly[2 * S + s]);
      v = fmaf(v, L, visc_poly[3 * S + s]);
      v = fmaf(v, L, visc_poly[4 * S + s]);
      float c = cond_poly[0 * S + s];
      c = fmaf(c, L, cond_poly[1 * S + s]);
      c = fmaf(c, L, cond_poly[2 * S + s]);
      c = fmaf(c, L, cond_poly[3 * S + s]);
      c = fmaf(c, L, cond_poly[4 * S + s]);
      condA = x * c;
      condB = x / c;
      ((float*)&XL[s])[row] = x;
      ((float*)&VL[s])[row] = v;
      ((float*)&U1[s])[row] = x * __builtin_amdgcn_rsqf(v);
      ((float*)&U2[s])[row] = x * __builtin_amdgcn_rcpf(v);
    }
    float scp = wave_sum(cpx);
    float sh = wave_sum(hy);
    float ss = wave_sum(sy);
    float sca = wave_sum(condA);
    float scb = wave_sum(condB);
    if (lane == 0) {
      pb[wid][0] = scp; pb[wid][1] = sh; pb[wid][2] = ss;
      pb[wid][3] = sca; pb[wid][4] = scb;
      if (half == 0) {
        rs_L[row] = L;
        rs_T[row] = T;
        rs_cfac[row] = cfac;
        rs_mW[row] = mW;
        rs_scale[row] = ATMF / (mW * P);
      }
    }
  }
  __syncthreads();

  // scalar outputs
  if (tid < RPB) {
    const int r = tid;
    float scp = pb[r][0] + pb[r + 4][0];
    float sh  = pb[r][1] + pb[r + 4][1];
    float ss  = pb[r][2] + pb[r + 4][2];
    float sca = pb[r][3] + pb[r + 4][3];
    float scb = pb[r][4] + pb[r + 4][4];
    float* orow = out + (size_t)(row0 + r) * OUT_COLS;
    orow[0] = RGASF * scp;
    orow[1] = RGASF * rs_T[r] * sh;
    orow[2] = RGASF * ss;
    orow[3 + NR + 1] = 0.5f * (sca + 1.0f / scb);
  }

  // ======== Concurrent worker stages (no barriers between them) ===========
  if (tid < 200) {
    // ---- Stage B: C_M2 = (C @ eff)*i3b + (1-i3b); thread owns q-quad ----
    const int q0 = tid * 4;
    float acc[4][4];
#pragma unroll
    for (int qi = 0; qi < 4; ++qi)
#pragma unroll
      for (int b = 0; b < RPB; ++b) acc[qi][b] = 0.0f;
#pragma unroll 4
    for (int s2 = 0; s2 < S; ++s2) {
      float4 e = *(const float4*)&eff[s2 * NR + q0];
      float4 xq = XL[s2];
#pragma unroll
      for (int qi = 0; qi < 4; ++qi)
#pragma unroll
        for (int b = 0; b < RPB; ++b)
          acc[qi][b] = fmaf(elem(xq, b), elem(e, qi), acc[qi][b]);
    }
    float cf[RPB];
#pragma unroll
    for (int b = 0; b < RPB; ++b) cf[b] = rs_cfac[b];
    float4 t3 = *(const float4*)&i3b[q0];
#pragma unroll
    for (int qi = 0; qi < 4; ++qi) {
      float tq = elem(t3, qi);
      float base = 1.0f - tq;
#pragma unroll
      for (int b = 0; b < RPB; ++b)
        out[(size_t)(row0 + b) * OUT_COLS + 3 + q0 + qi] =
            fmaf(acc[qi][b] * cf[b], tq, base);
    }
  } else if (tid >= 256 && tid < 384) {
    // ---- Stage C: viscosity denom + contribution; thread owns row i ----
    const int i = tid - 256;
    float contrib[RPB] = {0.0f, 0.0f, 0.0f, 0.0f};
    if (i < S) {
      const float mwi = mwl[i];
      const float lmi = ilm[i].y;
      float d0[RPB], d1[RPB], d2[RPB];
#pragma unroll
      for (int b = 0; b < RPB; ++b) { d0[b] = 0; d1[b] = 0; d2[b] = 0; }
#pragma unroll 2
      for (int k = 0; k < S; ++k) {
        float2 il = ilm[k];
        float A = 0.35355339059327373f *
                  __builtin_amdgcn_rsqf(1.0f + mwi * il.x);
        float B4 = __builtin_amdgcn_exp2f(0.25f * (il.y - lmi));
        float m1 = A * B4, m2 = m1 * B4;
        float4 xq = XL[k];
        float4 u1q = U1[k];
        float4 u2q = U2[k];
#pragma unroll
        for (int b = 0; b < RPB; ++b) {
          d0[b] = fmaf(A, elem(xq, b), d0[b]);
          d1[b] = fmaf(m1, elem(u1q, b), d1[b]);
          d2[b] = fmaf(m2, elem(u2q, b), d2[b]);
        }
      }
      float4 vq = VL[i];
      float4 xiq = XL[i];
#pragma unroll
      for (int b = 0; b < RPB; ++b) {
        float vi = elem(vq, b);
        float den = d0[b] + 2.0f * sqrtf(vi) * d1[b] + vi * d2[b];
        contrib[b] = elem(xiq, b) * vi / den;
      }
    }
#pragma unroll
    for (int b = 0; b < RPB; ++b) contrib[b] = wave_sum(contrib[b]);
    if (lane == 0) {
#pragma unroll
      for (int b = 0; b < RPB; ++b) psum[wid - 4][b] = contrib[b];
    }
  } else if (tid >= 384) {
    // ---- Stage D: mixture diffusion; thread owns column k ----
    const int k = tid - 384;
    if (k < S) {
      float Lb[RPB], acc[RPB];
#pragma unroll
      for (int b = 0; b < RPB; ++b) { Lb[b] = rs_L[b]; acc[b] = 0.0f; }
      const float* bp = bdiff_poly + k;
#pragma unroll 2
      for (int j = 0; j < S; ++j) {
        float c0 = bp[j * 100];
        float c1 = bp[10000 + j * 100];
        float c2 = bp[20000 + j * 100];
        float c3 = bp[30000 + j * 100];
        float c4 = bp[40000 + j * 100];
        float4 xq = XL[j];
        bool diag = (j == k);
#pragma unroll
        for (int b = 0; b < RPB; ++b) {
          float p = fmaf(c0, Lb[b], c1);
          p = fmaf(p, Lb[b], c2);
          p = fmaf(p, Lb[b], c3);
          p = fmaf(p, Lb[b], c4);
          float r = diag ? 0.0f : __builtin_amdgcn_rcpf(p);
          acc[b] = fmaf(elem(xq, b), r, acc[b]);
        }
      }
      float4 xkq = XL[k];
      float mwk = mwl[k];
#pragma unroll
      for (int b = 0; b < RPB; ++b) {
        float num = rs_mW[b] - elem(xkq, b) * mwk;   // XjWj
        out[(size_t)(row0 + b) * OUT_COLS + 3 + NR + 2 + k] =
            num * __builtin_amdgcn_rcpf(acc[b]) * rs_scale[b];
      }
    }
  }
  __syncthreads();

  if (tid < RPB) {
    out[(size_t)(row0 + tid) * OUT_COLS + 3 + NR] =
        psum[0][tid] + psum[1][tid];   // viscosities
  }
}

} // namespace

extern "C" void kernel_launch(void* const* d_in, const int* in_sizes, int n_in,
                              void* d_out, int out_size, void* d_ws, size_t ws_size,
                              hipStream_t stream) {
  const float* TPY        = (const float*)d_in[0];
  const float* mwp        = (const float*)d_in[1];
  const float* nasa_low   = (const float*)d_in[2];
  const float* nasa_high  = (const float*)d_in[3];
  const float* eff        = (const float*)d_in[4];
  const float* i3b        = (const float*)d_in[5];
  const float* visc_poly  = (const float*)d_in[6];
  const float* cond_poly  = (const float*)d_in[7];
  const float* bdiff_poly = (const float*)d_in[8];
  float* out = (float*)d_out;

  const int B = 2048;
  dim3 grid(B / RPB);
  chem_props_kernel<<<grid, NTH, 0, stream>>>(
      TPY, mwp, nasa_low, nasa_high, eff, i3b,
      visc_poly, cond_poly, bdiff_poly, out);
}